// Round 1
// baseline (963.680 us; speedup 1.0000x reference)
//
#include <hip/hip_runtime.h>
#include <hip/hip_bf16.h>
#include <stdint.h>

// Problem: B=64, C=256, H=W=64, 3x3 SAME conv, per-sample per-tap softmax mask.
// out[b,o,y,x] = sum_{tap,i} (mask[b,tap]*w[o,i,tap]) * inp[b,i,y+dy-1,x+dx-1]
// Implicit GEMM per sample: M=256(o), N=4096(y,x), K=2304(tap*256+i), bf16 MFMA.

typedef __hip_bfloat16 bf16;
using frag_ab = __attribute__((ext_vector_type(8))) short;  // 8 bf16 (4 VGPRs)
using frag_cd = __attribute__((ext_vector_type(4))) float;  // 4 fp32

#define AS1 __attribute__((address_space(1)))
#define AS3 __attribute__((address_space(3)))

#define NB 64
#define NC 256
#define NH 64
#define NW 64
#define HP 66
#define WP 66
#define KTOT 2304           // 9 * 256
#define XP_ELEMS ((size_t)NB * HP * WP * NC)          // 71,270,400... (64*66*66*256)
#define WB_ELEMS ((size_t)NB * NC * KTOT)             // 37,748,736

__device__ __forceinline__ void gld_lds16(const void* g, void* l) {
    __builtin_amdgcn_global_load_lds((const AS1 void*)g, (AS3 void*)l, 16, 0, 0);
}

// ---- prepass 1: softmax over 9 taps per sample ----
__global__ void softmax_kernel(const float* __restrict__ act, float* __restrict__ mask) {
    int b = threadIdx.x;
    if (b < NB) {
        float v[9], mx = -1e30f;
        #pragma unroll
        for (int i = 0; i < 9; i++) { v[i] = act[b * 9 + i]; mx = fmaxf(mx, v[i]); }
        float s = 0.f;
        #pragma unroll
        for (int i = 0; i < 9; i++) { v[i] = expf(v[i] - mx); s += v[i]; }
        float inv = 1.f / s;
        #pragma unroll
        for (int i = 0; i < 9; i++) mask[b * 9 + i] = v[i] * inv;
    }
}

// ---- prepass 2: Wb[b][o][tap*256+i] = bf16(mask[b,tap] * w[o,i,tap]) ----
// one thread per (b,o,tap,i-chunk-of-8); 16B coalesced writes, cached scattered reads
__global__ __launch_bounds__(256) void wscale_kernel(const float* __restrict__ w,
                                                     const float* __restrict__ mask,
                                                     bf16* __restrict__ Wb) {
    int id = blockIdx.x * 256 + threadIdx.x;      // total 64*256*9*32 = 4,718,592
    int ic8  = id & 31;
    int tap  = (id >> 5) % 9;
    int rest = (id >> 5) / 9;
    int o    = rest & 255;
    int b    = rest >> 8;
    float m = mask[b * 9 + tap];
    int i0 = ic8 * 8;
    union { bf16 h[8]; uint4 v; } u;
    #pragma unroll
    for (int q = 0; q < 8; q++) {
        float wv = w[((size_t)(o * 256 + i0 + q)) * 9 + tap];
        u.h[q] = __float2bfloat16(m * wv);
    }
    bf16* dst = Wb + ((size_t)(b * 256 + o)) * KTOT + tap * 256 + i0;
    *(uint4*)dst = u.v;
}

// ---- prepass 3: zero the pad border of Xp [b][66][66][256] ----
__global__ __launch_bounds__(256) void border_kernel(bf16* __restrict__ Xp) {
    int id = blockIdx.x * 256 + threadIdx.x;      // total 64*260*32 = 532,480
    int ch = id & 31;
    int px = (id >> 5) % 260;
    int b  = (id >> 5) / 260;
    int y, x;
    if (px < 66)       { y = 0;  x = px; }
    else if (px < 132) { y = 65; x = px - 66; }
    else { int e = px - 132; y = 1 + (e >> 1); x = (e & 1) * 65; }
    bf16* dst = Xp + (((size_t)b * HP + y) * WP + x) * NC + ch * 8;
    uint4 z; z.x = 0; z.y = 0; z.z = 0; z.w = 0;
    *(uint4*)dst = z;
}

// ---- prepass 4: NCHW fp32 -> padded NHWC bf16 via LDS transpose ----
// block handles (b, y, cblk of 64 channels) x full 64 x
__global__ __launch_bounds__(256) void pad_kernel(const float* __restrict__ inp,
                                                  bf16* __restrict__ Xp) {
    int bid = blockIdx.x;                  // b*256 + y*4 + cb
    int cb = bid & 3;
    int y  = (bid >> 2) & 63;
    int b  = bid >> 8;
    __shared__ bf16 tile[64][66];          // [x][c], pad 66 -> conflict-free b32
    int t = threadIdx.x;
    int tx = t & 63, tr = t >> 6;          // tr in 0..3
    const float* src = inp + (((size_t)b * NC + cb * 64) * NH + y) * NW + tx;
    #pragma unroll
    for (int ci = 0; ci < 8; ci++) {
        int c = tr * 16 + ci * 2;
        float v0 = src[(size_t)c * (NH * NW)];
        float v1 = src[(size_t)(c + 1) * (NH * NW)];
        union { bf16 h[2]; uint u; } pk;
        pk.h[0] = __float2bfloat16(v0);
        pk.h[1] = __float2bfloat16(v1);
        *(uint*)&tile[tx][c] = pk.u;
    }
    __syncthreads();
    #pragma unroll
    for (int pp = 0; pp < 2; pp++) {
        int x = pp * 32 + (t >> 3);
        int s = t & 7;
        // 4 x b32 LDS reads (66-pad keeps banks clean; 16B LDS read would misalign)
        uint u0 = *(const uint*)&tile[x][s * 8 + 0];
        uint u1 = *(const uint*)&tile[x][s * 8 + 2];
        uint u2 = *(const uint*)&tile[x][s * 8 + 4];
        uint u3 = *(const uint*)&tile[x][s * 8 + 6];
        uint4 val; val.x = u0; val.y = u1; val.z = u2; val.w = u3;
        bf16* dst = Xp + (((size_t)b * HP + (y + 1)) * WP + (x + 1)) * NC + cb * 64 + s * 8;
        *(uint4*)dst = val;
    }
}

// ---- main GEMM: per-sample out[o, n] = sum_k Wb[b][o][k] * Xp_patch[b][k][n] ----
// m97 structure: 128x128 tile, BK=32, 4 waves x (4x4) 16x16x32 bf16 MFMAs,
// global_load_lds width 16, [row][k] 64B LDS rows, 2-barrier K-loop.
__global__ __launch_bounds__(256) void gemm_kernel(const bf16* __restrict__ Wb,
                                                   const bf16* __restrict__ Xp,
                                                   float* __restrict__ out) {
    int bid = blockIdx.x;
    int nt = bid & 31;          // 32 N-tiles (2 rows x 64 cols each)
    int mt = (bid >> 5) & 1;    // 2 M-tiles of 128 o-channels
    int b  = bid >> 6;          // sample

    __shared__ bf16 As[128 * 32];   // [o][k] rows of 64B
    __shared__ bf16 Bs[128 * 32];   // [n][k] rows of 64B

    int t = threadIdx.x;
    int w = t >> 6;            // wave 0..3
    int l = t & 63;

    // staging lane map: LDS byte = j*4096 + w*1024 + l*16 -> row j*64+w*16+l/4, kchunk (l&3)*8
    int so = w * 16 + (l >> 2);    // 0..63
    int sk = (l & 3) * 8;

    char* AsB = (char*)As + w * 1024;   // wave-uniform LDS base
    char* BsB = (char*)Bs + w * 1024;

    const bf16* wrow = Wb + ((size_t)(b * 256 + mt * 128) + so) * KTOT + sk;
    const bf16* xbase = Xp + (size_t)b * HP * WP * NC;
    int vb = so * NC + sk;         // per-lane B offset (pixel col = so)

    int wm = w >> 1, wn = w & 1;
    int lm = l & 15;
    int lk = (l >> 4) * 8;

    frag_cd acc[4][4];
    #pragma unroll
    for (int r = 0; r < 4; r++)
        #pragma unroll
        for (int c = 0; c < 4; c++)
            #pragma unroll
            for (int q = 0; q < 4; q++) acc[r][c][q] = 0.f;

    const bf16* ap = As + (wm * 64 + lm) * 32 + lk;
    const bf16* bp = Bs + (wn * 64 + lm) * 32 + lk;

    #pragma unroll 1
    for (int tap = 0; tap < 9; tap++) {
        int dy = tap / 3, dx = tap % 3;                 // uniform -> SALU
        const bf16* a0 = wrow + tap * 256;
        const bf16* b0 = xbase + (((nt * 2 + dy) * WP) + dx) * NC + vb;
        const bf16* b1 = b0 + WP * NC;
        #pragma unroll
        for (int kk = 0; kk < 8; kk++) {
            __syncthreads();                            // prev compute done
            gld_lds16(a0,             AsB);
            gld_lds16(a0 + 64 * KTOT, AsB + 4096);
            gld_lds16(b0,             BsB);
            gld_lds16(b1,             BsB + 4096);
            __syncthreads();                            // loads visible
            frag_ab af[4], bfr[4];
            #pragma unroll
            for (int r = 0; r < 4; r++) af[r]  = *(const frag_ab*)(ap + r * 16 * 32);
            #pragma unroll
            for (int c = 0; c < 4; c++) bfr[c] = *(const frag_ab*)(bp + c * 16 * 32);
            #pragma unroll
            for (int r = 0; r < 4; r++)
                #pragma unroll
                for (int c = 0; c < 4; c++)
                    acc[r][c] = __builtin_amdgcn_mfma_f32_16x16x32_bf16(
                        af[r], bfr[c], acc[r][c], 0, 0, 0);
            a0 += 32; b0 += 32; b1 += 32;
        }
    }

    // epilogue: C/D layout col=lane&15 (n), row=(lane>>4)*4+reg (m)
    int col = lm;
    int rq = (l >> 4) * 4;
    #pragma unroll
    for (int r = 0; r < 4; r++) {
        #pragma unroll
        for (int c = 0; c < 4; c++) {
            int m = mt * 128 + wm * 64 + r * 16 + rq;
            int n = wn * 64 + c * 16 + col;
            float* po = out + ((size_t)(b * 256 + m)) * (NH * NW) + nt * 128 + n;
            #pragma unroll
            for (int q = 0; q < 4; q++) po[(size_t)q * (NH * NW)] = acc[r][c][q];
        }
    }
}

// ws too small -> recognizable diagnostic pattern
__global__ void diag_kernel(float* out) { out[threadIdx.x] = 12345.0f; }

extern "C" void kernel_launch(void* const* d_in, const int* in_sizes, int n_in,
                              void* d_out, int out_size, void* d_ws, size_t ws_size,
                              hipStream_t stream) {
    const float* inp = (const float*)d_in[0];
    const float* act = (const float*)d_in[1];
    const float* wgt = (const float*)d_in[2];
    float* out = (float*)d_out;

    size_t MASK_OFF = 0;
    size_t WB_OFF = 4096;
    size_t XP_OFF = WB_OFF + WB_ELEMS * sizeof(bf16);       // + 75,497,472
    size_t NEED  = XP_OFF + XP_ELEMS * sizeof(bf16);        // ~218.3 MB total

    if (ws_size < NEED) {
        diag_kernel<<<1, 256, 0, stream>>>(out);
        return;
    }

    float* mask = (float*)((char*)d_ws + MASK_OFF);
    bf16* Wb = (bf16*)((char*)d_ws + WB_OFF);
    bf16* Xp = (bf16*)((char*)d_ws + XP_OFF);

    softmax_kernel<<<1, 64, 0, stream>>>(act, mask);
    wscale_kernel<<<(NB * NC * 9 * 32) / 256, 256, 0, stream>>>(wgt, mask, Wb);
    border_kernel<<<(NB * 260 * 32) / 256, 256, 0, stream>>>(Xp);
    pad_kernel<<<NB * NH * 4, 256, 0, stream>>>(inp, Xp);
    gemm_kernel<<<NB * 2 * 32, 256, 0, stream>>>(Wb, Xp, out);
}

// Round 2
// 899.668 us; speedup vs baseline: 1.0712x; 1.0712x over previous
//
#include <hip/hip_runtime.h>
#include <hip/hip_bf16.h>
#include <stdint.h>

// B=64, C=256, H=W=64, 3x3 SAME conv, per-sample per-tap softmax mask.
// Implicit GEMM per sample: M=256(o), N=4096(y,x), K=2304(tap*256+i), bf16 MFMA.

typedef __hip_bfloat16 bf16;
using frag_ab = __attribute__((ext_vector_type(8))) short;  // 8 bf16 (4 VGPRs)
using frag_cd = __attribute__((ext_vector_type(4))) float;  // 4 fp32

#define AS1 __attribute__((address_space(1)))
#define AS3 __attribute__((address_space(3)))

#define NB 64
#define NC 256
#define NH 64
#define NW 64
#define HP 66
#define WP 66
#define KTOT 2304           // 9 * 256
#define XP_ELEMS ((size_t)NB * HP * WP * NC)
#define WB_ELEMS ((size_t)NB * NC * KTOT)
#define WT_ELEMS ((size_t)NC * KTOT)                   // 589,824 bf16

__device__ __forceinline__ void gld_lds16(const void* g, void* l) {
    __builtin_amdgcn_global_load_lds((const AS1 void*)g, (AS3 void*)l, 16, 0, 0);
}

// ---- prepass 1: softmax over 9 taps per sample ----
__global__ void softmax_kernel(const float* __restrict__ act, float* __restrict__ mask) {
    int b = threadIdx.x;
    if (b < NB) {
        float v[9], mx = -1e30f;
        #pragma unroll
        for (int i = 0; i < 9; i++) { v[i] = act[b * 9 + i]; mx = fmaxf(mx, v[i]); }
        float s = 0.f;
        #pragma unroll
        for (int i = 0; i < 9; i++) { v[i] = expf(v[i] - mx); s += v[i]; }
        float inv = 1.f / s;
        #pragma unroll
        for (int i = 0; i < 9; i++) mask[b * 9 + i] = v[i] * inv;
    }
}

// ---- prepass 2a: transpose w [o][i][tap] f32 -> Wt [o][tap][i] bf16 ----
// coalesced reads (flat o-slice is contiguous); LDS reorder; coalesced uint4 writes
__global__ __launch_bounds__(256) void wt_kernel(const float* __restrict__ w,
                                                 bf16* __restrict__ Wt) {
    int o = blockIdx.x;
    int t = threadIdx.x;
    __shared__ alignas(16) bf16 buf[KTOT];
    #pragma unroll
    for (int j = 0; j < 9; j++) {
        int idx = j * 256 + t;                 // flat within o-slice: i*9+tap
        float v = w[(size_t)o * KTOT + idx];
        int i = idx / 9, tap = idx - i * 9;
        buf[tap * 256 + i] = __float2bfloat16(v);
    }
    __syncthreads();
    const uint4* s = (const uint4*)buf;        // 288 chunks of 16B
    uint4* dst = (uint4*)(Wt + (size_t)o * KTOT);
    dst[t] = s[t];
    if (t < 32) dst[256 + t] = s[256 + t];
}

// ---- prepass 2b: Wb[b][o][tap*256+i] = bf16(mask[b,tap] * Wt[o][tap][i]) ----
// fully coalesced 16B reads + 16B writes
__global__ __launch_bounds__(256) void wscale_kernel(const bf16* __restrict__ Wt,
                                                     const float* __restrict__ mask,
                                                     bf16* __restrict__ Wb) {
    int id = blockIdx.x * 256 + threadIdx.x;   // total 64*256*288 = 4,718,592
    int chunk = id % 288;                      // 16B chunk within (b,o) row
    int rest  = id / 288;
    int o = rest & 255;
    int b = rest >> 8;
    int tap = chunk >> 5;                      // 32 chunks per tap
    float m = mask[b * 9 + tap];
    union { bf16 h[8]; uint4 v; } u;
    u.v = *(const uint4*)(Wt + (size_t)o * KTOT + chunk * 8);
    #pragma unroll
    for (int q = 0; q < 8; q++)
        u.h[q] = __float2bfloat16(m * __bfloat162float(u.h[q]));
    *(uint4*)(Wb + ((size_t)(b * 256 + o)) * KTOT + chunk * 8) = u.v;
}

// ---- prepass 3: zero the pad border of Xp [b][66][66][256] ----
__global__ __launch_bounds__(256) void border_kernel(bf16* __restrict__ Xp) {
    int id = blockIdx.x * 256 + threadIdx.x;
    int ch = id & 31;
    int px = (id >> 5) % 260;
    int b  = (id >> 5) / 260;
    int y, x;
    if (px < 66)       { y = 0;  x = px; }
    else if (px < 132) { y = 65; x = px - 66; }
    else { int e = px - 132; y = 1 + (e >> 1); x = (e & 1) * 65; }
    bf16* dst = Xp + (((size_t)b * HP + y) * WP + x) * NC + ch * 8;
    uint4 z; z.x = 0; z.y = 0; z.z = 0; z.w = 0;
    *(uint4*)dst = z;
}

// ---- prepass 4: NCHW fp32 -> padded NHWC bf16 via LDS transpose (float2 reads) ----
__global__ __launch_bounds__(256) void pad_kernel(const float* __restrict__ inp,
                                                  bf16* __restrict__ Xp) {
    int bid = blockIdx.x;                  // b*256 + y*4 + cb
    int cb = bid & 3;
    int y  = (bid >> 2) & 63;
    int b  = bid >> 8;
    __shared__ bf16 tile[64][66];          // [x][c], pad 66
    int t = threadIdx.x;
    int xp = (t & 31) * 2, tr = t >> 5;    // tr in 0..7
    const float* src = inp + (((size_t)b * NC + cb * 64) * NH + y) * NW + xp;
    #pragma unroll
    for (int ci = 0; ci < 4; ci++) {
        int c = tr * 8 + ci * 2;
        float2 v0 = *(const float2*)(src + (size_t)c * (NH * NW));
        float2 v1 = *(const float2*)(src + (size_t)(c + 1) * (NH * NW));
        union { bf16 h[2]; uint u; } p0, p1;
        p0.h[0] = __float2bfloat16(v0.x); p0.h[1] = __float2bfloat16(v1.x);
        p1.h[0] = __float2bfloat16(v0.y); p1.h[1] = __float2bfloat16(v1.y);
        *(uint*)&tile[xp][c]     = p0.u;
        *(uint*)&tile[xp + 1][c] = p1.u;
    }
    __syncthreads();
    #pragma unroll
    for (int pp = 0; pp < 2; pp++) {
        int x = pp * 32 + (t >> 3);
        int s = t & 7;
        uint u0 = *(const uint*)&tile[x][s * 8 + 0];
        uint u1 = *(const uint*)&tile[x][s * 8 + 2];
        uint u2 = *(const uint*)&tile[x][s * 8 + 4];
        uint u3 = *(const uint*)&tile[x][s * 8 + 6];
        uint4 val; val.x = u0; val.y = u1; val.z = u2; val.w = u3;
        bf16* dst = Xp + (((size_t)b * HP + (y + 1)) * WP + (x + 1)) * NC + cb * 64 + s * 8;
        *(uint4*)dst = val;
    }
}

// ---- main GEMM: m97 structure + k-chunk rotation swizzle (bank-conflict fix) ----
// Swizzle: chunk c of LDS row R holds logical k-chunk (c - (R>>1)) & 3.
// Staging lane l (fixed dest chunk l&3, row w*16+(l>>2), (R>>1)&3 == (l>>3)&3):
//   loads logical chunk q = ((l&3) - ((l>>3)&3)) & 3.
// Frag read lane l (logical chunk l>>4, row base+lm, (R>>1)&3 == (lm>>1)&3):
//   reads stored chunk ((l>>4) + ((l>>1)&3)) & 3  -> 2-way bank aliasing (free).
__global__ __launch_bounds__(256) void gemm_kernel(const bf16* __restrict__ Wb,
                                                   const bf16* __restrict__ Xp,
                                                   float* __restrict__ out) {
    int bid = blockIdx.x;
    int nt = bid & 31;          // 32 N-tiles (2 rows x 64 cols each)
    int mt = (bid >> 5) & 1;    // 2 M-tiles of 128 o-channels
    int b  = bid >> 6;          // sample

    __shared__ bf16 As[128 * 32];   // [o][k] rows of 64B
    __shared__ bf16 Bs[128 * 32];   // [n][k] rows of 64B

    int t = threadIdx.x;
    int w = t >> 6;
    int l = t & 63;

    int so = w * 16 + (l >> 2);                    // staged row 0..63
    int sq = ((l & 3) - ((l >> 3) & 3)) & 3;       // swizzled logical k-chunk
    int sk = sq * 8;                               // element offset

    char* AsB = (char*)As + w * 1024;
    char* BsB = (char*)Bs + w * 1024;

    const bf16* wrow = Wb + ((size_t)(b * 256 + mt * 128) + so) * KTOT + sk;
    const bf16* xbase = Xp + (size_t)b * HP * WP * NC;
    int vb = so * NC + sk;

    int wm = w >> 1, wn = w & 1;
    int lm = l & 15;
    int lkq = (((l >> 4) + ((l >> 1) & 3)) & 3) * 8;   // swizzled frag chunk

    frag_cd acc[4][4];
    #pragma unroll
    for (int r = 0; r < 4; r++)
        #pragma unroll
        for (int c = 0; c < 4; c++)
            #pragma unroll
            for (int q = 0; q < 4; q++) acc[r][c][q] = 0.f;

    const bf16* ap = As + (wm * 64 + lm) * 32 + lkq;
    const bf16* bp = Bs + (wn * 64 + lm) * 32 + lkq;

    #pragma unroll 1
    for (int tap = 0; tap < 9; tap++) {
        int dy = tap / 3, dx = tap % 3;
        const bf16* a0 = wrow + tap * 256;
        const bf16* b0 = xbase + (((nt * 2 + dy) * WP) + dx) * NC + vb;
        const bf16* b1 = b0 + WP * NC;
        #pragma unroll
        for (int kk = 0; kk < 8; kk++) {
            __syncthreads();
            gld_lds16(a0,             AsB);
            gld_lds16(a0 + 64 * KTOT, AsB + 4096);
            gld_lds16(b0,             BsB);
            gld_lds16(b1,             BsB + 4096);
            __syncthreads();
            frag_ab af[4], bfr[4];
            #pragma unroll
            for (int r = 0; r < 4; r++) af[r]  = *(const frag_ab*)(ap + r * 16 * 32);
            #pragma unroll
            for (int c = 0; c < 4; c++) bfr[c] = *(const frag_ab*)(bp + c * 16 * 32);
            #pragma unroll
            for (int r = 0; r < 4; r++)
                #pragma unroll
                for (int c = 0; c < 4; c++)
                    acc[r][c] = __builtin_amdgcn_mfma_f32_16x16x32_bf16(
                        af[r], bfr[c], acc[r][c], 0, 0, 0);
            a0 += 32; b0 += 32; b1 += 32;
        }
    }

    int col = lm;
    int rq = (l >> 4) * 4;
    #pragma unroll
    for (int r = 0; r < 4; r++) {
        #pragma unroll
        for (int c = 0; c < 4; c++) {
            int m = mt * 128 + wm * 64 + r * 16 + rq;
            int n = wn * 64 + c * 16 + col;
            float* po = out + ((size_t)(b * 256 + m)) * (NH * NW) + nt * 128 + n;
            #pragma unroll
            for (int q = 0; q < 4; q++) po[(size_t)q * (NH * NW)] = acc[r][c][q];
        }
    }
}

__global__ void diag_kernel(float* out) { out[threadIdx.x] = 12345.0f; }

extern "C" void kernel_launch(void* const* d_in, const int* in_sizes, int n_in,
                              void* d_out, int out_size, void* d_ws, size_t ws_size,
                              hipStream_t stream) {
    const float* inp = (const float*)d_in[0];
    const float* act = (const float*)d_in[1];
    const float* wgt = (const float*)d_in[2];
    float* out = (float*)d_out;

    size_t MASK_OFF = 0;
    size_t WB_OFF = 4096;
    size_t XP_OFF = WB_OFF + WB_ELEMS * sizeof(bf16);
    size_t NEED  = XP_OFF + XP_ELEMS * sizeof(bf16);   // same as round 1

    if (ws_size < NEED) {
        diag_kernel<<<1, 256, 0, stream>>>(out);
        return;
    }

    float* mask = (float*)((char*)d_ws + MASK_OFF);
    bf16* Wb = (bf16*)((char*)d_ws + WB_OFF);
    bf16* Xp = (bf16*)((char*)d_ws + XP_OFF);
    // Wt is transient: lives at the head of the Xp region, fully consumed by
    // wscale_kernel BEFORE border/pad write Xp (same-stream serialization).
    bf16* Wt = Xp;

    softmax_kernel<<<1, 64, 0, stream>>>(act, mask);
    wt_kernel<<<NC, 256, 0, stream>>>(wgt, Wt);
    wscale_kernel<<<(NB * NC * 288) / 256, 256, 0, stream>>>(Wt, mask, Wb);
    border_kernel<<<(NB * 260 * 32) / 256, 256, 0, stream>>>(Xp);
    pad_kernel<<<NB * NH * 4, 256, 0, stream>>>(inp, Xp);
    gemm_kernel<<<NB * 2 * 32, 256, 0, stream>>>(Wb, Xp, out);
}